// Round 7
// baseline (87.102 us; speedup 1.0000x reference)
//
#include <hip/hip_runtime.h>

// MoE gate fp32, B=65536 D=1024 E=8 K=2.
// R7: R3 geometry (wave = 8 row-slots x 8 col-splitters, 2 rows/lane,
// chunk=32, x prefetch depth 1) but NO LDS: weights read directly from
// global (64 KB, L2-resident). Clean A/B vs R3 on the LDS-pipe question.

#define BLOCK 512
#define DD 1024
#define EE 8
#define ROWS_PER_WAVE 16
#define ROWS_PER_BLOCK ((BLOCK / 64) * ROWS_PER_WAVE)   // 128
#define CHUNK 32
#define NCHUNK (DD / CHUNK)                             // 32

typedef float vf4 __attribute__((ext_vector_type(4)));

__global__ __launch_bounds__(BLOCK, 4) void moe_gate_kernel(
    const float* __restrict__ x,
    const float* __restrict__ gate_w,
    const float* __restrict__ gate_b,
    const float* __restrict__ expert_w,
    const float* __restrict__ expert_b,
    const int* __restrict__ kp,
    float* __restrict__ out)
{
    const int tid  = threadIdx.x;
    const int lane = tid & 63;
    const int wave = tid >> 6;
    const int s = lane >> 3;     // row-slot (0..7), owns rows {2s, 2s+1}
    const int j = lane & 7;      // column splitter (0..7), cols c*32 + j*4

    const int row0 = blockIdx.x * ROWS_PER_BLOCK + wave * ROWS_PER_WAVE + 2 * s;
    const float* xr0 = x + (size_t)row0 * DD + j * 4;
    const float* xr1 = xr0 + DD;

    const float* wg = gate_w   + j * 4;   // this lane's gate-weight base
    const float* we = expert_w + j * 4;   // this lane's expert-weight base

    float acc0[16], acc1[16];
#pragma unroll
    for (int i = 0; i < 16; ++i) { acc0[i] = 0.f; acc1[i] = 0.f; }

    auto step = [&](int c, const vf4& x0, const vf4& x1) {
        const int wc = c * CHUNK;
#pragma unroll
        for (int o = 0; o < EE; ++o) {
            vf4 w1 = *(const vf4*)(wg + o * DD + wc);
            acc0[o] = fmaf(x0.x, w1.x, acc0[o]);
            acc1[o] = fmaf(x1.x, w1.x, acc1[o]);
            acc0[o] = fmaf(x0.y, w1.y, acc0[o]);
            acc1[o] = fmaf(x1.y, w1.y, acc1[o]);
            acc0[o] = fmaf(x0.z, w1.z, acc0[o]);
            acc1[o] = fmaf(x1.z, w1.z, acc1[o]);
            acc0[o] = fmaf(x0.w, w1.w, acc0[o]);
            acc1[o] = fmaf(x1.w, w1.w, acc1[o]);
            vf4 w2 = *(const vf4*)(we + o * DD + wc);
            acc0[8 + o] = fmaf(x0.x, w2.x, acc0[8 + o]);
            acc1[8 + o] = fmaf(x1.x, w2.x, acc1[8 + o]);
            acc0[8 + o] = fmaf(x0.y, w2.y, acc0[8 + o]);
            acc1[8 + o] = fmaf(x1.y, w2.y, acc1[8 + o]);
            acc0[8 + o] = fmaf(x0.z, w2.z, acc0[8 + o]);
            acc1[8 + o] = fmaf(x1.z, w2.z, acc1[8 + o]);
            acc0[8 + o] = fmaf(x0.w, w2.w, acc0[8 + o]);
            acc1[8 + o] = fmaf(x1.w, w2.w, acc1[8 + o]);
        }
    };

    // software-pipelined: prefetch next chunk's x while computing current
    vf4 a0 = *(const vf4*)(xr0);
    vf4 a1 = *(const vf4*)(xr1);
#pragma unroll 1
    for (int c = 0; c < NCHUNK - 1; ++c) {
        vf4 b0 = *(const vf4*)(xr0 + (c + 1) * CHUNK);
        vf4 b1 = *(const vf4*)(xr1 + (c + 1) * CHUNK);
        step(c, a0, a1);
        a0 = b0; a1 = b1;
    }
    step(NCHUNK - 1, a0, a1);

    // reduce across the 8 column-splitter lanes (once per kernel)
#pragma unroll
    for (int i = 0; i < 16; ++i) {
        acc0[i] += __shfl_xor(acc0[i], 1);
        acc1[i] += __shfl_xor(acc1[i], 1);
        acc0[i] += __shfl_xor(acc0[i], 2);
        acc1[i] += __shfl_xor(acc1[i], 2);
        acc0[i] += __shfl_xor(acc0[i], 4);
        acc1[i] += __shfl_xor(acc1[i], 4);
    }

    if (j == 0) {
        const int k = *kp;
#pragma unroll
        for (int r = 0; r < 2; ++r) {
            const float* acc = r ? acc1 : acc0;
            float gl[8], eo[8], p[8];
#pragma unroll
            for (int e = 0; e < EE; ++e) {
                gl[e] = acc[e] + gate_b[e];
                eo[e] = acc[8 + e] + expert_b[e];
            }
            float m = gl[0];
#pragma unroll
            for (int e = 1; e < EE; ++e) m = fmaxf(m, gl[e]);
            float Z = 0.f;
#pragma unroll
            for (int e = 0; e < EE; ++e) { p[e] = __expf(gl[e] - m); Z += p[e]; }

            float res = 0.f;
            if (k >= EE) {
#pragma unroll
                for (int e = 0; e < EE; ++e) res += p[e] * eo[e];
            } else {
                float pv[8];
#pragma unroll
                for (int e = 0; e < EE; ++e) pv[e] = p[e];
                for (int t = 0; t < k; ++t) {
                    float bv = pv[0];
#pragma unroll
                    for (int e = 1; e < EE; ++e) bv = fmaxf(bv, pv[e]);
                    float sel = 0.f;
                    bool found = false;
#pragma unroll
                    for (int e = 0; e < EE; ++e) {   // first-match == lax.top_k tie rule
                        bool is = (!found) && (pv[e] == bv);
                        sel = is ? eo[e] : sel;
                        pv[e] = is ? -1.f : pv[e];
                        found = found || is;
                    }
                    res += bv * sel;
                }
            }
            out[row0 + r] = res / Z;
        }
    }
}

extern "C" void kernel_launch(void* const* d_in, const int* in_sizes, int n_in,
                              void* d_out, int out_size, void* d_ws, size_t ws_size,
                              hipStream_t stream) {
    const float* x  = (const float*)d_in[0];
    const float* gw = (const float*)d_in[1];
    const float* gb = (const float*)d_in[2];
    const float* ew = (const float*)d_in[3];
    const float* eb = (const float*)d_in[4];
    const int*   kp = (const int*)d_in[5];
    float* out = (float*)d_out;

    const int B = out_size;               // 65536
    dim3 grid(B / ROWS_PER_BLOCK), block(BLOCK);
    moe_gate_kernel<<<grid, block, 0, stream>>>(x, gw, gb, ew, eb, kp, out);
}

// Round 8
// 55.926 us; speedup vs baseline: 1.5575x; 1.5575x over previous
//
#include <hip/hip_runtime.h>

// MoE gate fp32, B=65536 D=1024 E=8 K=2.
// R8: occupancy push. BLOCK=1024 (16 waves), weights (64KB f32) in LDS once
// per block, 2 blocks/CU = 32 waves/CU (8/SIMD) -- requires VGPR<=64, so slim
// geometry: 1 row/lane, wave = 8 rows x 8 col-splitters, acc[16], depth-1
// x prefetch. ds_read_b128 = 128B distinct, 8-way broadcast, conflict-free.

#define BLOCK 1024
#define DD 1024
#define EE 8
#define ROWS_PER_WAVE 8
#define ROWS_PER_BLOCK ((BLOCK / 64) * ROWS_PER_WAVE)   // 128
#define CHUNK 32
#define NCHUNK (DD / CHUNK)                             // 32

typedef float vf4 __attribute__((ext_vector_type(4)));

__global__ __launch_bounds__(BLOCK, 8) void moe_gate_kernel(
    const float* __restrict__ x,
    const float* __restrict__ gate_w,
    const float* __restrict__ gate_b,
    const float* __restrict__ expert_w,
    const float* __restrict__ expert_b,
    const int* __restrict__ kp,
    float* __restrict__ out)
{
    __shared__ float wlds[2 * EE * DD];   // 64 KiB: [gate 8x1024 | expert 8x1024]

    const int tid = threadIdx.x;

    // one-time weight preload (coalesced float4)
    {
        const float4* g4 = (const float4*)gate_w;
        const float4* e4 = (const float4*)expert_w;
        float4* w4 = (float4*)wlds;
#pragma unroll
        for (int i = 0; i < (EE * DD / 4) / BLOCK; ++i) {
            int idx = i * BLOCK + tid;
            w4[idx] = g4[idx];
            w4[EE * DD / 4 + idx] = e4[idx];
        }
    }
    __syncthreads();

    const int lane = tid & 63;
    const int wave = tid >> 6;
    const int s = lane >> 3;     // row-slot (0..7), 1 row per lane
    const int j = lane & 7;      // column splitter (0..7), cols c*32 + j*4

    const int row = blockIdx.x * ROWS_PER_BLOCK + wave * ROWS_PER_WAVE + s;
    const float* xr = x + (size_t)row * DD + j * 4;

    const float* wb = wlds + j * 4;      // this lane's weight base

    float acc[16];
#pragma unroll
    for (int i = 0; i < 16; ++i) acc[i] = 0.f;

    auto step = [&](int c, const vf4& xv) {
        const int wc = c * CHUNK;
#pragma unroll
        for (int o = 0; o < 16; ++o) {
            vf4 w = *(const vf4*)(wb + o * DD + wc);
            acc[o] = fmaf(xv.x, w.x, acc[o]);
            acc[o] = fmaf(xv.y, w.y, acc[o]);
            acc[o] = fmaf(xv.z, w.z, acc[o]);
            acc[o] = fmaf(xv.w, w.w, acc[o]);
        }
    };

    // software-pipelined: prefetch next chunk's x while computing current
    vf4 cur = *(const vf4*)(xr);
#pragma unroll 1
    for (int c = 0; c < NCHUNK - 1; ++c) {
        vf4 nxt = *(const vf4*)(xr + (c + 1) * CHUNK);
        step(c, cur);
        cur = nxt;
    }
    step(NCHUNK - 1, cur);

    // reduce across the 8 column-splitter lanes (once per kernel)
#pragma unroll
    for (int i = 0; i < 16; ++i) {
        acc[i] += __shfl_xor(acc[i], 1);
        acc[i] += __shfl_xor(acc[i], 2);
        acc[i] += __shfl_xor(acc[i], 4);
    }

    if (j == 0) {
        const int k = *kp;
        float gl[8], eo[8], p[8];
#pragma unroll
        for (int e = 0; e < EE; ++e) {
            gl[e] = acc[e] + gate_b[e];
            eo[e] = acc[8 + e] + expert_b[e];
        }
        float m = gl[0];
#pragma unroll
        for (int e = 1; e < EE; ++e) m = fmaxf(m, gl[e]);
        float Z = 0.f;
#pragma unroll
        for (int e = 0; e < EE; ++e) { p[e] = __expf(gl[e] - m); Z += p[e]; }

        float res = 0.f;
        if (k >= EE) {
#pragma unroll
            for (int e = 0; e < EE; ++e) res += p[e] * eo[e];
        } else {
            float pv[8];
#pragma unroll
            for (int e = 0; e < EE; ++e) pv[e] = p[e];
            for (int t = 0; t < k; ++t) {
                float bv = pv[0];
#pragma unroll
                for (int e = 1; e < EE; ++e) bv = fmaxf(bv, pv[e]);
                float sel = 0.f;
                bool found = false;
#pragma unroll
                for (int e = 0; e < EE; ++e) {   // first-match == lax.top_k tie rule
                    bool is = (!found) && (pv[e] == bv);
                    sel = is ? eo[e] : sel;
                    pv[e] = is ? -1.f : pv[e];
                    found = found || is;
                }
                res += bv * sel;
            }
        }
        out[row] = res / Z;
    }
}

extern "C" void kernel_launch(void* const* d_in, const int* in_sizes, int n_in,
                              void* d_out, int out_size, void* d_ws, size_t ws_size,
                              hipStream_t stream) {
    const float* x  = (const float*)d_in[0];
    const float* gw = (const float*)d_in[1];
    const float* gb = (const float*)d_in[2];
    const float* ew = (const float*)d_in[3];
    const float* eb = (const float*)d_in[4];
    const int*   kp = (const int*)d_in[5];
    float* out = (float*)d_out;

    const int B = out_size;               // 65536
    dim3 grid(B / ROWS_PER_BLOCK), block(BLOCK);
    moe_gate_kernel<<<grid, block, 0, stream>>>(x, gw, gb, ew, eb, kp, out);
}

// Round 9
// 51.206 us; speedup vs baseline: 1.7010x; 1.0922x over previous
//
#include <hip/hip_runtime.h>

// MoE gate fp32, B=65536 D=1024 E=8 K=2.
// R9 = R3 + prefetch depth 2 (single-variable change).
// Wave = 8 row-slots x 8 col-splitters, 2 rows per lane (16 rows/wave).
// Weights in LDS (broadcast ds_read_b128, conflict-free). Chunks c+1 and c+2
// kept in flight (4 outstanding dwordx4/lane) to cover ~900cy HBM latency.

#define BLOCK 512
#define DD 1024
#define EE 8
#define ROWS_PER_WAVE 16
#define ROWS_PER_BLOCK ((BLOCK / 64) * ROWS_PER_WAVE)   // 128
#define CHUNK 32
#define NCHUNK (DD / CHUNK)                             // 32

typedef float vf4 __attribute__((ext_vector_type(4)));

__global__ __launch_bounds__(BLOCK, 4) void moe_gate_kernel(
    const float* __restrict__ x,
    const float* __restrict__ gate_w,
    const float* __restrict__ gate_b,
    const float* __restrict__ expert_w,
    const float* __restrict__ expert_b,
    const int* __restrict__ kp,
    float* __restrict__ out)
{
    __shared__ float wlds[2 * EE * DD];   // 64 KiB: [gate 8x1024 | expert 8x1024]

    const int tid = threadIdx.x;

    // one-time weight preload (coalesced float4)
    {
        const float4* g4 = (const float4*)gate_w;
        const float4* e4 = (const float4*)expert_w;
        float4* w4 = (float4*)wlds;
#pragma unroll
        for (int i = 0; i < (EE * DD / 4) / BLOCK; ++i) {
            int idx = i * BLOCK + tid;
            w4[idx] = g4[idx];
            w4[EE * DD / 4 + idx] = e4[idx];
        }
    }
    __syncthreads();

    const int lane = tid & 63;
    const int wave = tid >> 6;
    const int s = lane >> 3;     // row-slot (0..7), owns rows {2s, 2s+1}
    const int j = lane & 7;      // column splitter (0..7), cols c*32 + j*4

    const int row0 = blockIdx.x * ROWS_PER_BLOCK + wave * ROWS_PER_WAVE + 2 * s;
    const float* xr0 = x + (size_t)row0 * DD + j * 4;
    const float* xr1 = xr0 + DD;

    const float* wb = wlds + j * 4;      // this lane's weight base

    float acc0[16], acc1[16];
#pragma unroll
    for (int i = 0; i < 16; ++i) { acc0[i] = 0.f; acc1[i] = 0.f; }

    auto step = [&](int c, const vf4& x0, const vf4& x1) {
        const int wc = c * CHUNK;
#pragma unroll
        for (int o = 0; o < 16; ++o) {
            vf4 w = *(const vf4*)(wb + o * DD + wc);
            acc0[o] = fmaf(x0.x, w.x, acc0[o]);
            acc1[o] = fmaf(x1.x, w.x, acc1[o]);
            acc0[o] = fmaf(x0.y, w.y, acc0[o]);
            acc1[o] = fmaf(x1.y, w.y, acc1[o]);
            acc0[o] = fmaf(x0.z, w.z, acc0[o]);
            acc1[o] = fmaf(x1.z, w.z, acc1[o]);
            acc0[o] = fmaf(x0.w, w.w, acc0[o]);
            acc1[o] = fmaf(x1.w, w.w, acc1[o]);
        }
    };

    // software-pipelined, depth 2: chunks c+1 and c+2 in flight
    vf4 a0 = *(const vf4*)(xr0);
    vf4 a1 = *(const vf4*)(xr1);
    vf4 b0 = *(const vf4*)(xr0 + CHUNK);
    vf4 b1 = *(const vf4*)(xr1 + CHUNK);
#pragma unroll 1
    for (int c = 0; c < NCHUNK - 2; ++c) {
        vf4 n0 = *(const vf4*)(xr0 + (c + 2) * CHUNK);
        vf4 n1 = *(const vf4*)(xr1 + (c + 2) * CHUNK);
        step(c, a0, a1);
        a0 = b0; a1 = b1;
        b0 = n0; b1 = n1;
    }
    step(NCHUNK - 2, a0, a1);
    step(NCHUNK - 1, b0, b1);

    // reduce across the 8 column-splitter lanes (once per kernel)
#pragma unroll
    for (int i = 0; i < 16; ++i) {
        acc0[i] += __shfl_xor(acc0[i], 1);
        acc1[i] += __shfl_xor(acc1[i], 1);
        acc0[i] += __shfl_xor(acc0[i], 2);
        acc1[i] += __shfl_xor(acc1[i], 2);
        acc0[i] += __shfl_xor(acc0[i], 4);
        acc1[i] += __shfl_xor(acc1[i], 4);
    }

    if (j == 0) {
        const int k = *kp;
#pragma unroll
        for (int r = 0; r < 2; ++r) {
            const float* acc = r ? acc1 : acc0;
            float gl[8], eo[8], p[8];
#pragma unroll
            for (int e = 0; e < EE; ++e) {
                gl[e] = acc[e] + gate_b[e];
                eo[e] = acc[8 + e] + expert_b[e];
            }
            float m = gl[0];
#pragma unroll
            for (int e = 1; e < EE; ++e) m = fmaxf(m, gl[e]);
            float Z = 0.f;
#pragma unroll
            for (int e = 0; e < EE; ++e) { p[e] = __expf(gl[e] - m); Z += p[e]; }

            float res = 0.f;
            if (k >= EE) {
#pragma unroll
                for (int e = 0; e < EE; ++e) res += p[e] * eo[e];
            } else {
                float pv[8];
#pragma unroll
                for (int e = 0; e < EE; ++e) pv[e] = p[e];
                for (int t = 0; t < k; ++t) {
                    float bv = pv[0];
#pragma unroll
                    for (int e = 1; e < EE; ++e) bv = fmaxf(bv, pv[e]);
                    float sel = 0.f;
                    bool found = false;
#pragma unroll
                    for (int e = 0; e < EE; ++e) {   // first-match == lax.top_k tie rule
                        bool is = (!found) && (pv[e] == bv);
                        sel = is ? eo[e] : sel;
                        pv[e] = is ? -1.f : pv[e];
                        found = found || is;
                    }
                    res += bv * sel;
                }
            }
            out[row0 + r] = res / Z;
        }
    }
}

extern "C" void kernel_launch(void* const* d_in, const int* in_sizes, int n_in,
                              void* d_out, int out_size, void* d_ws, size_t ws_size,
                              hipStream_t stream) {
    const float* x  = (const float*)d_in[0];
    const float* gw = (const float*)d_in[1];
    const float* gb = (const float*)d_in[2];
    const float* ew = (const float*)d_in[3];
    const float* eb = (const float*)d_in[4];
    const int*   kp = (const int*)d_in[5];
    float* out = (float*)d_out;

    const int B = out_size;               // 65536
    dim3 grid(B / ROWS_PER_BLOCK), block(BLOCK);
    moe_gate_kernel<<<grid, block, 0, stream>>>(x, gw, gb, ew, eb, kp, out);
}